// Round 6
// baseline (3161.972 us; speedup 1.0000x reference)
//
#include <hip/hip_runtime.h>

#define NN 100000
#define NE 1600000
#define NG 1024
#define NODE_IN 163
#define SLOPE 0.01f
#define NBUK 391      // ceil(100000/256)
#define BUKSH 8       // 256 nodes per bucket
#define EPB 8192      // edges per partition block
#define NBLK ((NE + EPB - 1) / EPB)   // 196

// ---------------- CSR build (privatized counting sort; round-4, verified) -------------
__global__ void k_hist(const int* __restrict__ dst, int* __restrict__ bh, int E) {
  __shared__ int h[NBUK];
  for (int i = threadIdx.x; i < NBUK; i += 256) h[i] = 0;
  __syncthreads();
  int beg = blockIdx.x * EPB, end = min(E, beg + EPB);
  for (int e = beg + threadIdx.x; e < end; e += 256) atomicAdd(&h[dst[e] >> BUKSH], 1);
  __syncthreads();
  for (int i = threadIdx.x; i < NBUK; i += 256) bh[blockIdx.x * NBUK + i] = h[i];
}

__global__ void k_bucket_scan(int* __restrict__ bh, int* __restrict__ btot) {
  __shared__ int s[256];
  int bucket = blockIdx.x, tid = threadIdx.x;
  int v = (tid < NBLK) ? bh[tid * NBUK + bucket] : 0;
  s[tid] = v;
  __syncthreads();
  for (int off = 1; off < 256; off <<= 1) {
    int t = (tid >= off) ? s[tid - off] : 0;
    __syncthreads();
    s[tid] += t;
    __syncthreads();
  }
  if (tid < NBLK) bh[tid * NBUK + bucket] = s[tid] - v;
  if (tid == 255) btot[bucket] = s[255];
}

__global__ void k_btot_scan(const int* __restrict__ btot, int* __restrict__ boffs, int E) {
  __shared__ int s[512];
  int tid = threadIdx.x;
  int v = (tid < NBUK) ? btot[tid] : 0;
  s[tid] = v;
  __syncthreads();
  for (int off = 1; off < 512; off <<= 1) {
    int t = (tid >= off) ? s[tid - off] : 0;
    __syncthreads();
    s[tid] += t;
    __syncthreads();
  }
  if (tid < NBUK) boffs[tid] = s[tid] - v;
  if (tid == 0) boffs[NBUK] = E;
}

__global__ void k_scatter(const int* __restrict__ src, const int* __restrict__ dst,
                          const int* __restrict__ bh, const int* __restrict__ boffs,
                          unsigned* __restrict__ bedge, int E) {
  __shared__ int cur[NBUK];
  for (int i = threadIdx.x; i < NBUK; i += 256)
    cur[i] = boffs[i] + bh[blockIdx.x * NBUK + i];
  __syncthreads();
  int beg = blockIdx.x * EPB, end = min(E, beg + EPB);
  for (int e = beg + threadIdx.x; e < end; e += 256) {
    int d = dst[e];
    int pos = atomicAdd(&cur[d >> BUKSH], 1);
    bedge[pos] = (unsigned)src[e] | ((unsigned)(d & 255) << 17);
  }
}

__global__ void k_b2csr(const unsigned* __restrict__ bedge, const int* __restrict__ boffs,
                        int* __restrict__ offs, float* __restrict__ dis,
                        int* __restrict__ csr, int N) {
  __shared__ int lcnt[256];
  __shared__ int s[256];
  __shared__ int lcur[256];
  int b = blockIdx.x, tid = threadIdx.x;
  int beg = boffs[b], end = boffs[b + 1];
  lcnt[tid] = 0;
  __syncthreads();
  for (int e = beg + tid; e < end; e += 256) atomicAdd(&lcnt[bedge[e] >> 17], 1);
  __syncthreads();
  int v = lcnt[tid];
  s[tid] = v;
  __syncthreads();
  for (int off = 1; off < 256; off <<= 1) {
    int t = (tid >= off) ? s[tid - off] : 0;
    __syncthreads();
    s[tid] += t;
    __syncthreads();
  }
  int o = s[tid] - v;
  int node = (b << BUKSH) + tid;
  if (node <= N) offs[node] = beg + o;
  if (node < N) dis[node] = rsqrtf((float)(v + 1));
  lcur[tid] = o;
  __syncthreads();
  for (int e = beg + tid; e < end; e += 256) {
    unsigned w = bedge[e];
    int p = atomicAdd(&lcur[w >> 17], 1);
    csr[beg + p] = (int)(w & 0x1FFFFu);
  }
}

// ---------------- GEMM: chunked-K, dbuf X+W in LDS, lane=col, wave=16 rows ------------
// Inner loop: per k0 (4 k's): 4x ds_read_b32 W (2-way, free) + 16x b128 X broadcast
// (wave-uniform, conflict-free) + 64 FMA.  One barrier per chunk (T14 reg staging).

__device__ __forceinline__ void comp44(const float* __restrict__ sXc,
                                       const float* __restrict__ sWc,
                                       int wv, int lane, float* acc, int nk0, int pitch) {
  const float* xw = sXc + wv * 16 * pitch;
  for (int k0 = 0; k0 < nk0 * 4; k0 += 4) {
    float w0 = sWc[(k0 + 0) * 64 + lane];
    float w1 = sWc[(k0 + 1) * 64 + lane];
    float w2 = sWc[(k0 + 2) * 64 + lane];
    float w3 = sWc[(k0 + 3) * 64 + lane];
    #pragma unroll
    for (int r = 0; r < 16; ++r) {
      float4 xv = *(const float4*)(xw + r * pitch + k0);
      acc[r] += xv.x * w0;
      acc[r] += xv.y * w1;
      acc[r] += xv.z * w2;
      acc[r] += xv.w * w3;
    }
  }
}

// ---- K=163: 4 chunks of 41 real k's stored in pitch-44 (slots 41..43 zeroed) ----
__device__ __forceinline__ void xs163(const float* __restrict__ X, int t, int N,
                                      int tid, int c, float4* rx) {
  #pragma unroll
  for (int m = 0; m < 3; ++m) {
    int s = tid + 256 * m;
    float4 v = make_float4(0.f, 0.f, 0.f, 0.f);
    if (s < 704) {
      int r = s / 11, j = s % 11;
      long gr = (long)t * 64 + r;
      if (gr < N) {
        const float* xp = X + gr * 163 + c * 41;
        float tmp[4];
        #pragma unroll
        for (int d = 0; d < 4; ++d) {
          int kk = 4 * j + d;
          tmp[d] = (kk < 41 && c * 41 + kk < 163) ? xp[kk] : 0.f;
        }
        v = make_float4(tmp[0], tmp[1], tmp[2], tmp[3]);
      }
    }
    rx[m] = v;
  }
}
__device__ __forceinline__ void xw163(float* __restrict__ b, int tid, const float4* rx) {
  #pragma unroll
  for (int m = 0; m < 3; ++m) {
    int s = tid + 256 * m;
    if (s < 704) { int r = s / 11, j = s % 11; *(float4*)(b + r * 44 + 4 * j) = rx[m]; }
  }
}
__device__ __forceinline__ void ws163(const float* __restrict__ W, int tid, int c, float4* rw) {
  #pragma unroll
  for (int m = 0; m < 3; ++m) {
    int s = tid + 256 * m;
    float4 v = make_float4(0.f, 0.f, 0.f, 0.f);
    if (s < 704) {
      int k = s / 16, c4 = s % 16;
      int gk = c * 41 + k;
      if (k < 41 && gk < 163) v = *(const float4*)(W + (size_t)gk * 64 + 4 * c4);
    }
    rw[m] = v;
  }
}
__device__ __forceinline__ void ww163(float* __restrict__ b, int tid, const float4* rw) {
  #pragma unroll
  for (int m = 0; m < 3; ++m) {
    int s = tid + 256 * m;
    if (s < 704) { int k = s / 16, c4 = s % 16; *(float4*)(b + k * 64 + 4 * c4) = rw[m]; }
  }
}

__launch_bounds__(256)
__global__ void k_gemm163(const float* __restrict__ X, const float* __restrict__ W,
                          const float* __restrict__ disv, float* __restrict__ Y, int N) {
  __shared__ __align__(16) float sX[2][64 * 44];
  __shared__ __align__(16) float sW[2][44 * 64];
  const int tid = threadIdx.x, lane = tid & 63, wv = tid >> 6;
  const int t = blockIdx.x;
  float4 rx[3], rw[3];
  xs163(X, t, N, tid, 0, rx); ws163(W, tid, 0, rw);
  xw163(sX[0], tid, rx);      ww163(sW[0], tid, rw);
  __syncthreads();
  float acc[16];
  #pragma unroll
  for (int r = 0; r < 16; ++r) acc[r] = 0.f;
  for (int c = 0; c < 4; ++c) {
    if (c < 3) { xs163(X, t, N, tid, c + 1, rx); ws163(W, tid, c + 1, rw); }
    comp44(sX[c & 1], sW[c & 1], wv, lane, acc, 11, 44);
    if (c < 3) {
      xw163(sX[(c + 1) & 1], tid, rx); ww163(sW[(c + 1) & 1], tid, rw);
      __syncthreads();
    }
  }
  long base = (long)t * 64 + wv * 16;
  #pragma unroll
  for (int r = 0; r < 16; ++r) {
    long row = base + r;
    if (row < N) Y[row * 64 + lane] = acc[r] * disv[row];
  }
}

// ---- K=64: 2 chunks of 32, all-float4 staging ----
__device__ __forceinline__ void xs64(const float* __restrict__ X, int t, int N,
                                     int tid, int c, float4* rx) {
  #pragma unroll
  for (int m = 0; m < 2; ++m) {
    int s = tid + 256 * m;               // 512 slots: r = s/8, j = s%8
    int r = s >> 3, j = s & 7;
    long gr = (long)t * 64 + r;
    rx[m] = (gr < N) ? *(const float4*)(X + gr * 64 + c * 32 + 4 * j)
                     : make_float4(0.f, 0.f, 0.f, 0.f);
  }
}
__device__ __forceinline__ void xw64(float* __restrict__ b, int tid, const float4* rx) {
  #pragma unroll
  for (int m = 0; m < 2; ++m) {
    int s = tid + 256 * m;
    int r = s >> 3, j = s & 7;
    *(float4*)(b + r * 32 + 4 * j) = rx[m];
  }
}
__device__ __forceinline__ void ws64(const float* __restrict__ W, int tid, int c, float4* rw) {
  #pragma unroll
  for (int m = 0; m < 2; ++m) {
    int s = tid + 256 * m;               // 512 slots: k = s/16, c4 = s%16
    int k = s >> 4, c4 = s & 15;
    rw[m] = *(const float4*)(W + (size_t)(c * 32 + k) * 64 + 4 * c4);
  }
}
__device__ __forceinline__ void ww64(float* __restrict__ b, int tid, const float4* rw) {
  #pragma unroll
  for (int m = 0; m < 2; ++m) {
    int s = tid + 256 * m;
    int k = s >> 4, c4 = s & 15;
    *(float4*)(b + k * 64 + 4 * c4) = rw[m];
  }
}

__launch_bounds__(256)
__global__ void k_gemm64(const float* __restrict__ X, const float* __restrict__ W,
                         const float* __restrict__ disv, float* __restrict__ Y, int N) {
  __shared__ __align__(16) float sX[2][64 * 32];
  __shared__ __align__(16) float sW[2][32 * 64];
  const int tid = threadIdx.x, lane = tid & 63, wv = tid >> 6;
  const int t = blockIdx.x;
  float4 rx[2], rw[2];
  xs64(X, t, N, tid, 0, rx); ws64(W, tid, 0, rw);
  xw64(sX[0], tid, rx);      ww64(sW[0], tid, rw);
  __syncthreads();
  float acc[16];
  #pragma unroll
  for (int r = 0; r < 16; ++r) acc[r] = 0.f;
  for (int c = 0; c < 2; ++c) {
    if (c < 1) { xs64(X, t, N, tid, 1, rx); ws64(W, tid, 1, rw); }
    comp44(sX[c & 1], sW[c & 1], wv, lane, acc, 8, 32);
    if (c < 1) {
      xw64(sX[1], tid, rx); ww64(sW[1], tid, rw);
      __syncthreads();
    }
  }
  long base = (long)t * 64 + wv * 16;
  #pragma unroll
  for (int r = 0; r < 16; ++r) {
    long row = base + r;
    if (row < N) Y[row * 64 + lane] = acc[r] * disv[row];
  }
}

// One wave per node: Hout[i] = lrelu( (Hps[i] + sum_{e->i} Hps[src]) * dis[i] + b )
__launch_bounds__(256)
__global__ void k_agg(const float* __restrict__ Hps, const int* __restrict__ offs,
                      const int* __restrict__ csr, const float* __restrict__ dis,
                      const float* __restrict__ bias, float* __restrict__ Hout, int N) {
  int node = blockIdx.x * 4 + (threadIdx.x >> 6);
  if (node >= N) return;
  int lane = threadIdx.x & 63;
  int beg = offs[node], end = offs[node + 1];
  float acc = Hps[(size_t)node * 64 + lane];
  int e = beg;
  for (; e + 4 <= end; e += 4) {
    int s0 = csr[e], s1 = csr[e + 1], s2 = csr[e + 2], s3 = csr[e + 3];
    acc += Hps[(size_t)s0 * 64 + lane];
    acc += Hps[(size_t)s1 * 64 + lane];
    acc += Hps[(size_t)s2 * 64 + lane];
    acc += Hps[(size_t)s3 * 64 + lane];
  }
  for (; e < end; ++e) acc += Hps[(size_t)csr[e] * 64 + lane];
  acc = acc * dis[node] + bias[lane];
  Hout[(size_t)node * 64 + lane] = (acc > 0.f) ? acc : SLOPE * acc;
}

// One wave per graph: mean-pool + fc1 + lrelu + fc2
__launch_bounds__(64)
__global__ void k_pool(const float* __restrict__ H, const int* __restrict__ batch,
                       const float* __restrict__ f1W, const float* __restrict__ f1b,
                       const float* __restrict__ f2W, const float* __restrict__ f2b,
                       float* __restrict__ out, int N) {
  int g = blockIdx.x;
  int lane = threadIdx.x;
  int lo = 0, hi = N;
  while (lo < hi) { int m = (lo + hi) >> 1; if (batch[m] < g) lo = m + 1; else hi = m; }
  int beg = lo;
  hi = N;
  while (lo < hi) { int m = (lo + hi) >> 1; if (batch[m] < g + 1) lo = m + 1; else hi = m; }
  int end = lo;
  float acc = 0.f;
  for (int r = beg; r < end; ++r) acc += H[(size_t)r * 64 + lane];
  float c = (float)(end - beg);
  acc /= (c < 1.f ? 1.f : c);
  __shared__ float p[64];
  p[lane] = acc;
  __syncthreads();
  float q = f1b[lane];
  #pragma unroll
  for (int k = 0; k < 64; ++k) q += p[k] * f1W[k * 64 + lane];
  q = (q > 0.f) ? q : SLOPE * q;
  float v = q * f2W[lane];
  #pragma unroll
  for (int off = 32; off > 0; off >>= 1) v += __shfl_down(v, off, 64);
  if (lane == 0) out[g] = v + f2b[0];
}

extern "C" void kernel_launch(void* const* d_in, const int* in_sizes, int n_in,
                              void* d_out, int out_size, void* d_ws, size_t ws_size,
                              hipStream_t stream) {
  const float* x    = (const float*)d_in[0];
  const int*  eidx  = (const int*)d_in[1];
  const int*  batch = (const int*)d_in[2];
  const float* W0 = (const float*)d_in[3];
  const float* b0 = (const float*)d_in[4];
  const float* W1 = (const float*)d_in[5];
  const float* b1 = (const float*)d_in[6];
  const float* W2 = (const float*)d_in[7];
  const float* b2 = (const float*)d_in[8];
  const float* f1W = (const float*)d_in[9];
  const float* f1b = (const float*)d_in[10];
  const float* f2W = (const float*)d_in[11];
  const float* f2b = (const float*)d_in[12];
  float* out = (float*)d_out;

  const int N = NN, E = NE;
  const int* src  = eidx;
  const int* dstp = eidx + E;

  const size_t NPAD = 100096;
  char* w = (char*)d_ws;
  float* bufA  = (float*)w; w += NPAD * 64 * 4;   // bedge aliases bufA (dead until gemm0)
  float* bufB  = (float*)w; w += NPAD * 64 * 4;
  int*   csr   = (int*)w;   w += (size_t)E * 4;
  int*   offs  = (int*)w;   w += (size_t)(N + 4) * 4;
  float* dis   = (float*)w; w += (size_t)N * 4;
  int*   bh    = (int*)w;   w += (size_t)NBLK * NBUK * 4;
  int*   btot  = (int*)w;   w += (NBUK + 1) * 4;
  int*   boffs = (int*)w;   w += (NBUK + 1) * 4;
  unsigned* bedge = (unsigned*)bufA;

  k_hist<<<NBLK, 256, 0, stream>>>(dstp, bh, E);
  k_bucket_scan<<<NBUK, 256, 0, stream>>>(bh, btot);
  k_btot_scan<<<1, 512, 0, stream>>>(btot, boffs, E);
  k_scatter<<<NBLK, 256, 0, stream>>>(src, dstp, bh, boffs, bedge, E);
  k_b2csr<<<NBUK, 256, 0, stream>>>(bedge, boffs, offs, dis, csr, N);

  const int NT = (N + 63) / 64;   // 1563
  k_gemm163<<<NT, 256, 0, stream>>>(x, W0, dis, bufA, N);
  k_agg<<<(N + 3) / 4, 256, 0, stream>>>(bufA, offs, csr, dis, b0, bufB, N);
  k_gemm64<<<NT, 256, 0, stream>>>(bufB, W1, dis, bufA, N);
  k_agg<<<(N + 3) / 4, 256, 0, stream>>>(bufA, offs, csr, dis, b1, bufB, N);
  k_gemm64<<<NT, 256, 0, stream>>>(bufB, W2, dis, bufA, N);
  k_agg<<<(N + 3) / 4, 256, 0, stream>>>(bufA, offs, csr, dis, b2, bufB, N);
  k_pool<<<NG, 64, 0, stream>>>(bufB, batch, f1W, f1b, f2W, f2b, out, N);
}

// Round 7
// 1115.862 us; speedup vs baseline: 2.8337x; 2.8337x over previous
//
#include <hip/hip_runtime.h>

#define NN 100000
#define NE 1600000
#define NG 1024
#define NODE_IN 163
#define SLOPE 0.01f
#define NBUK 391      // ceil(100000/256)
#define BUKSH 8       // 256 nodes per bucket
#define EPB 8192      // edges per partition block
#define NBLK ((NE + EPB - 1) / EPB)   // 196

// ---------------- CSR build (privatized counting sort; round-4, verified) -------------
__global__ void k_hist(const int* __restrict__ dst, int* __restrict__ bh, int E) {
  __shared__ int h[NBUK];
  for (int i = threadIdx.x; i < NBUK; i += 256) h[i] = 0;
  __syncthreads();
  int beg = blockIdx.x * EPB, end = min(E, beg + EPB);
  for (int e = beg + threadIdx.x; e < end; e += 256) atomicAdd(&h[dst[e] >> BUKSH], 1);
  __syncthreads();
  for (int i = threadIdx.x; i < NBUK; i += 256) bh[blockIdx.x * NBUK + i] = h[i];
}

__global__ void k_bucket_scan(int* __restrict__ bh, int* __restrict__ btot) {
  __shared__ int s[256];
  int bucket = blockIdx.x, tid = threadIdx.x;
  int v = (tid < NBLK) ? bh[tid * NBUK + bucket] : 0;
  s[tid] = v;
  __syncthreads();
  for (int off = 1; off < 256; off <<= 1) {
    int t = (tid >= off) ? s[tid - off] : 0;
    __syncthreads();
    s[tid] += t;
    __syncthreads();
  }
  if (tid < NBLK) bh[tid * NBUK + bucket] = s[tid] - v;
  if (tid == 255) btot[bucket] = s[255];
}

__global__ void k_btot_scan(const int* __restrict__ btot, int* __restrict__ boffs, int E) {
  __shared__ int s[512];
  int tid = threadIdx.x;
  int v = (tid < NBUK) ? btot[tid] : 0;
  s[tid] = v;
  __syncthreads();
  for (int off = 1; off < 512; off <<= 1) {
    int t = (tid >= off) ? s[tid - off] : 0;
    __syncthreads();
    s[tid] += t;
    __syncthreads();
  }
  if (tid < NBUK) boffs[tid] = s[tid] - v;
  if (tid == 0) boffs[NBUK] = E;
}

__global__ void k_scatter(const int* __restrict__ src, const int* __restrict__ dst,
                          const int* __restrict__ bh, const int* __restrict__ boffs,
                          unsigned* __restrict__ bedge, int E) {
  __shared__ int cur[NBUK];
  for (int i = threadIdx.x; i < NBUK; i += 256)
    cur[i] = boffs[i] + bh[blockIdx.x * NBUK + i];
  __syncthreads();
  int beg = blockIdx.x * EPB, end = min(E, beg + EPB);
  for (int e = beg + threadIdx.x; e < end; e += 256) {
    int d = dst[e];
    int pos = atomicAdd(&cur[d >> BUKSH], 1);
    bedge[pos] = (unsigned)src[e] | ((unsigned)(d & 255) << 17);
  }
}

__global__ void k_b2csr(const unsigned* __restrict__ bedge, const int* __restrict__ boffs,
                        int* __restrict__ offs, float* __restrict__ dis,
                        int* __restrict__ csr, int N) {
  __shared__ int lcnt[256];
  __shared__ int s[256];
  __shared__ int lcur[256];
  int b = blockIdx.x, tid = threadIdx.x;
  int beg = boffs[b], end = boffs[b + 1];
  lcnt[tid] = 0;
  __syncthreads();
  for (int e = beg + tid; e < end; e += 256) atomicAdd(&lcnt[bedge[e] >> 17], 1);
  __syncthreads();
  int v = lcnt[tid];
  s[tid] = v;
  __syncthreads();
  for (int off = 1; off < 256; off <<= 1) {
    int t = (tid >= off) ? s[tid - off] : 0;
    __syncthreads();
    s[tid] += t;
    __syncthreads();
  }
  int o = s[tid] - v;
  int node = (b << BUKSH) + tid;
  if (node <= N) offs[node] = beg + o;
  if (node < N) dis[node] = rsqrtf((float)(v + 1));
  lcur[tid] = o;
  __syncthreads();
  for (int e = beg + tid; e < end; e += 256) {
    unsigned w = bedge[e];
    int p = atomicAdd(&lcur[w >> 17], 1);
    csr[beg + p] = (int)(w & 0x1FFFFu);
  }
}

// ---------------- GEMM: 256-row tile, 8x8 microtile, k-major X in LDS -----------------
// Wave = 64 rows x 64 cols; lane (i,j): rows xoff..xoff+7 (contig), cols c0..c0+7.
// Per k: 2x ds_read_b128 X (2-way alias, free) + 2x b128 W + 64 FMA -> FMA-bound 2.7x.
// LDS 40KB dbuf -> 4 blocks/CU; all index math pow-2; acc statically indexed.
template<int K>
__launch_bounds__(256, 4)
__global__ void k_gemm(const float* __restrict__ X, const float* __restrict__ W,
                       const float* __restrict__ disv, float* __restrict__ Y, int N) {
  constexpr int KC = (K + 15) >> 4;
  __shared__ float sX[2][16 * 256];
  __shared__ float sW[2][16 * 64];
  const int tid = threadIdx.x;
  const int lane = tid & 63, wv = tid >> 6;
  const int xoff = wv * 64 + ((lane >> 3) << 3);   // row within 256-row tile
  const int c0 = (lane & 7) << 3;                  // col
  const long gbase = (long)blockIdx.x * 256;
  const int wk = tid >> 4, wc = (tid & 15) << 2;   // W staging slot

  float4 rx[4];
  float4 rw;
  const long gr = gbase + tid;
  const bool rok = gr < (long)N;
  const float* xr = X + gr * K;

  // ---- stage chunk c into registers (global -> reg) ----
  auto loadX = [&](int c) {
    const float* xp = xr + c * 16;
    #pragma unroll
    for (int m = 0; m < 4; ++m) {
      float4 v = make_float4(0.f, 0.f, 0.f, 0.f);
      if (rok) {
        int kk = c * 16 + 4 * m;
        if (kk + 4 <= K) v = *(const float4*)(xp + 4 * m);
        else {
          float t0 = (kk + 0 < K) ? xp[4 * m + 0] : 0.f;
          float t1 = (kk + 1 < K) ? xp[4 * m + 1] : 0.f;
          float t2 = (kk + 2 < K) ? xp[4 * m + 2] : 0.f;
          v = make_float4(t0, t1, t2, 0.f);
        }
      }
      rx[m] = v;
    }
  };
  auto loadW = [&](int c) {
    int gk = c * 16 + wk;
    rw = (gk < K) ? *(const float4*)(W + (size_t)gk * 64 + wc)
                  : make_float4(0.f, 0.f, 0.f, 0.f);
  };
  auto writeLDS = [&](int b) {
    float* xb = sX[b];
    #pragma unroll
    for (int m = 0; m < 4; ++m) {      // transpose to k-major; conflict-free b32
      xb[(4 * m + 0) * 256 + tid] = rx[m].x;
      xb[(4 * m + 1) * 256 + tid] = rx[m].y;
      xb[(4 * m + 2) * 256 + tid] = rx[m].z;
      xb[(4 * m + 3) * 256 + tid] = rx[m].w;
    }
    *(float4*)(sW[b] + wk * 64 + wc) = rw;
  };

  loadX(0); loadW(0); writeLDS(0);

  float acc[64];
  #pragma unroll
  for (int i = 0; i < 64; ++i) acc[i] = 0.f;

  #pragma unroll 1
  for (int c = 0; c < KC; ++c) {
    if (c + 1 < KC) { loadX(c + 1); loadW(c + 1); }   // issue early (T14)
    __syncthreads();
    const float* sXc = sX[c & 1];
    const float* sWc = sW[c & 1];
    #pragma unroll
    for (int k = 0; k < 16; ++k) {
      float4 xa = *(const float4*)(sXc + k * 256 + xoff);
      float4 xb = *(const float4*)(sXc + k * 256 + xoff + 4);
      float4 wa = *(const float4*)(sWc + k * 64 + c0);
      float4 wb = *(const float4*)(sWc + k * 64 + c0 + 4);
      float xr8[8] = {xa.x, xa.y, xa.z, xa.w, xb.x, xb.y, xb.z, xb.w};
      float wc8[8] = {wa.x, wa.y, wa.z, wa.w, wb.x, wb.y, wb.z, wb.w};
      #pragma unroll
      for (int r = 0; r < 8; ++r) {
        #pragma unroll
        for (int q = 0; q < 8; ++q) acc[r * 8 + q] += xr8[r] * wc8[q];
      }
    }
    if (c + 1 < KC) writeLDS((c + 1) & 1);            // write late (other buffer)
  }

  #pragma unroll
  for (int r = 0; r < 8; ++r) {
    long row = gbase + xoff + r;
    if (row < N) {
      float d = disv[row];
      float* yp = Y + row * 64 + c0;
      *(float4*)(yp + 0) = make_float4(acc[r*8+0]*d, acc[r*8+1]*d, acc[r*8+2]*d, acc[r*8+3]*d);
      *(float4*)(yp + 4) = make_float4(acc[r*8+4]*d, acc[r*8+5]*d, acc[r*8+6]*d, acc[r*8+7]*d);
    }
  }
}

// One wave per node: Hout[i] = lrelu( (Hps[i] + sum_{e->i} Hps[src]) * dis[i] + b )
__launch_bounds__(256)
__global__ void k_agg(const float* __restrict__ Hps, const int* __restrict__ offs,
                      const int* __restrict__ csr, const float* __restrict__ dis,
                      const float* __restrict__ bias, float* __restrict__ Hout, int N) {
  int node = blockIdx.x * 4 + (threadIdx.x >> 6);
  if (node >= N) return;
  int lane = threadIdx.x & 63;
  int beg = offs[node], end = offs[node + 1];
  float acc = Hps[(size_t)node * 64 + lane];
  int e = beg;
  for (; e + 4 <= end; e += 4) {
    int s0 = csr[e], s1 = csr[e + 1], s2 = csr[e + 2], s3 = csr[e + 3];
    acc += Hps[(size_t)s0 * 64 + lane];
    acc += Hps[(size_t)s1 * 64 + lane];
    acc += Hps[(size_t)s2 * 64 + lane];
    acc += Hps[(size_t)s3 * 64 + lane];
  }
  for (; e < end; ++e) acc += Hps[(size_t)csr[e] * 64 + lane];
  acc = acc * dis[node] + bias[lane];
  Hout[(size_t)node * 64 + lane] = (acc > 0.f) ? acc : SLOPE * acc;
}

// One wave per graph: mean-pool + fc1 + lrelu + fc2
__launch_bounds__(64)
__global__ void k_pool(const float* __restrict__ H, const int* __restrict__ batch,
                       const float* __restrict__ f1W, const float* __restrict__ f1b,
                       const float* __restrict__ f2W, const float* __restrict__ f2b,
                       float* __restrict__ out, int N) {
  int g = blockIdx.x;
  int lane = threadIdx.x;
  int lo = 0, hi = N;
  while (lo < hi) { int m = (lo + hi) >> 1; if (batch[m] < g) lo = m + 1; else hi = m; }
  int beg = lo;
  hi = N;
  while (lo < hi) { int m = (lo + hi) >> 1; if (batch[m] < g + 1) lo = m + 1; else hi = m; }
  int end = lo;
  float acc = 0.f;
  for (int r = beg; r < end; ++r) acc += H[(size_t)r * 64 + lane];
  float c = (float)(end - beg);
  acc /= (c < 1.f ? 1.f : c);
  __shared__ float p[64];
  p[lane] = acc;
  __syncthreads();
  float q = f1b[lane];
  #pragma unroll
  for (int k = 0; k < 64; ++k) q += p[k] * f1W[k * 64 + lane];
  q = (q > 0.f) ? q : SLOPE * q;
  float v = q * f2W[lane];
  #pragma unroll
  for (int off = 32; off > 0; off >>= 1) v += __shfl_down(v, off, 64);
  if (lane == 0) out[g] = v + f2b[0];
}

extern "C" void kernel_launch(void* const* d_in, const int* in_sizes, int n_in,
                              void* d_out, int out_size, void* d_ws, size_t ws_size,
                              hipStream_t stream) {
  const float* x    = (const float*)d_in[0];
  const int*  eidx  = (const int*)d_in[1];
  const int*  batch = (const int*)d_in[2];
  const float* W0 = (const float*)d_in[3];
  const float* b0 = (const float*)d_in[4];
  const float* W1 = (const float*)d_in[5];
  const float* b1 = (const float*)d_in[6];
  const float* W2 = (const float*)d_in[7];
  const float* b2 = (const float*)d_in[8];
  const float* f1W = (const float*)d_in[9];
  const float* f1b = (const float*)d_in[10];
  const float* f2W = (const float*)d_in[11];
  const float* f2b = (const float*)d_in[12];
  float* out = (float*)d_out;

  const int N = NN, E = NE;
  const int* src  = eidx;
  const int* dstp = eidx + E;

  const size_t NPAD = 100096;
  char* w = (char*)d_ws;
  float* bufA  = (float*)w; w += NPAD * 64 * 4;   // bedge aliases bufA (dead until gemm0)
  float* bufB  = (float*)w; w += NPAD * 64 * 4;
  int*   csr   = (int*)w;   w += (size_t)E * 4;
  int*   offs  = (int*)w;   w += (size_t)(N + 4) * 4;
  float* dis   = (float*)w; w += (size_t)N * 4;
  int*   bh    = (int*)w;   w += (size_t)NBLK * NBUK * 4;
  int*   btot  = (int*)w;   w += (NBUK + 1) * 4;
  int*   boffs = (int*)w;   w += (NBUK + 1) * 4;
  unsigned* bedge = (unsigned*)bufA;

  k_hist<<<NBLK, 256, 0, stream>>>(dstp, bh, E);
  k_bucket_scan<<<NBUK, 256, 0, stream>>>(bh, btot);
  k_btot_scan<<<1, 512, 0, stream>>>(btot, boffs, E);
  k_scatter<<<NBLK, 256, 0, stream>>>(src, dstp, bh, boffs, bedge, E);
  k_b2csr<<<NBUK, 256, 0, stream>>>(bedge, boffs, offs, dis, csr, N);

  const int NTB = (N + 255) / 256;   // 391
  k_gemm<NODE_IN><<<NTB, 256, 0, stream>>>(x, W0, dis, bufA, N);
  k_agg<<<(N + 3) / 4, 256, 0, stream>>>(bufA, offs, csr, dis, b0, bufB, N);
  k_gemm<64><<<NTB, 256, 0, stream>>>(bufB, W1, dis, bufA, N);
  k_agg<<<(N + 3) / 4, 256, 0, stream>>>(bufA, offs, csr, dis, b1, bufB, N);
  k_gemm<64><<<NTB, 256, 0, stream>>>(bufB, W2, dis, bufA, N);
  k_agg<<<(N + 3) / 4, 256, 0, stream>>>(bufA, offs, csr, dis, b2, bufB, N);
  k_pool<<<NG, 64, 0, stream>>>(bufB, batch, f1W, f1b, f2W, f2b, out, N);
}

// Round 8
// 665.667 us; speedup vs baseline: 4.7501x; 1.6763x over previous
//
#include <hip/hip_runtime.h>

#define NN 100000
#define NE 1600000
#define NG 1024
#define NODE_IN 163
#define SLOPE 0.01f
#define NBUK 391      // ceil(100000/256)
#define BUKSH 8       // 256 nodes per bucket
#define EPB 8192      // edges per partition block
#define NBLK ((NE + EPB - 1) / EPB)   // 196

// ---------------- CSR build (privatized counting sort; round-4, verified) -------------
__global__ void k_hist(const int* __restrict__ dst, int* __restrict__ bh, int E) {
  __shared__ int h[NBUK];
  for (int i = threadIdx.x; i < NBUK; i += 256) h[i] = 0;
  __syncthreads();
  int beg = blockIdx.x * EPB, end = min(E, beg + EPB);
  for (int e = beg + threadIdx.x; e < end; e += 256) atomicAdd(&h[dst[e] >> BUKSH], 1);
  __syncthreads();
  for (int i = threadIdx.x; i < NBUK; i += 256) bh[blockIdx.x * NBUK + i] = h[i];
}

__global__ void k_bucket_scan(int* __restrict__ bh, int* __restrict__ btot) {
  __shared__ int s[256];
  int bucket = blockIdx.x, tid = threadIdx.x;
  int v = (tid < NBLK) ? bh[tid * NBUK + bucket] : 0;
  s[tid] = v;
  __syncthreads();
  for (int off = 1; off < 256; off <<= 1) {
    int t = (tid >= off) ? s[tid - off] : 0;
    __syncthreads();
    s[tid] += t;
    __syncthreads();
  }
  if (tid < NBLK) bh[tid * NBUK + bucket] = s[tid] - v;
  if (tid == 255) btot[bucket] = s[255];
}

__global__ void k_btot_scan(const int* __restrict__ btot, int* __restrict__ boffs, int E) {
  __shared__ int s[512];
  int tid = threadIdx.x;
  int v = (tid < NBUK) ? btot[tid] : 0;
  s[tid] = v;
  __syncthreads();
  for (int off = 1; off < 512; off <<= 1) {
    int t = (tid >= off) ? s[tid - off] : 0;
    __syncthreads();
    s[tid] += t;
    __syncthreads();
  }
  if (tid < NBUK) boffs[tid] = s[tid] - v;
  if (tid == 0) boffs[NBUK] = E;
}

__global__ void k_scatter(const int* __restrict__ src, const int* __restrict__ dst,
                          const int* __restrict__ bh, const int* __restrict__ boffs,
                          unsigned* __restrict__ bedge, int E) {
  __shared__ int cur[NBUK];
  for (int i = threadIdx.x; i < NBUK; i += 256)
    cur[i] = boffs[i] + bh[blockIdx.x * NBUK + i];
  __syncthreads();
  int beg = blockIdx.x * EPB, end = min(E, beg + EPB);
  for (int e = beg + threadIdx.x; e < end; e += 256) {
    int d = dst[e];
    int pos = atomicAdd(&cur[d >> BUKSH], 1);
    bedge[pos] = (unsigned)src[e] | ((unsigned)(d & 255) << 17);
  }
}

__global__ void k_b2csr(const unsigned* __restrict__ bedge, const int* __restrict__ boffs,
                        int* __restrict__ offs, float* __restrict__ dis,
                        int* __restrict__ csr, int N) {
  __shared__ int lcnt[256];
  __shared__ int s[256];
  __shared__ int lcur[256];
  int b = blockIdx.x, tid = threadIdx.x;
  int beg = boffs[b], end = boffs[b + 1];
  lcnt[tid] = 0;
  __syncthreads();
  for (int e = beg + tid; e < end; e += 256) atomicAdd(&lcnt[bedge[e] >> 17], 1);
  __syncthreads();
  int v = lcnt[tid];
  s[tid] = v;
  __syncthreads();
  for (int off = 1; off < 256; off <<= 1) {
    int t = (tid >= off) ? s[tid - off] : 0;
    __syncthreads();
    s[tid] += t;
    __syncthreads();
  }
  int o = s[tid] - v;
  int node = (b << BUKSH) + tid;
  if (node <= N) offs[node] = beg + o;
  if (node < N) dis[node] = rsqrtf((float)(v + 1));
  lcur[tid] = o;
  __syncthreads();
  for (int e = beg + tid; e < end; e += 256) {
    unsigned w = bedge[e];
    int p = atomicAdd(&lcur[w >> 17], 1);
    csr[beg + p] = (int)(w & 0x1FFFFu);
  }
}

// ---------------- GEMM: 256-row tile, 8x8 microtile, k-major X in LDS -----------------
// Wave = 64 rows x 64 cols; lane (i,j): rows xoff..xoff+7 (contig), cols c0..c0+7.
// Per k: 2x ds_read_b128 X (2-way alias, free) + 2x b128 W + 64 FMA -> FMA-bound 2.7x.
// launch_bounds(256,2): VGPR cap 256 (needs ~140-160; (256,4)'s 128 cap spilled acc
// to scratch -> 1.8 GB HBM traffic, round-7 post-mortem).
template<int K>
__launch_bounds__(256, 2)
__global__ void k_gemm(const float* __restrict__ X, const float* __restrict__ W,
                       const float* __restrict__ disv, float* __restrict__ Y, int N) {
  constexpr int KC = (K + 15) >> 4;
  __shared__ float sX[2][16 * 256];
  __shared__ float sW[2][16 * 64];
  const int tid = threadIdx.x;
  const int lane = tid & 63, wv = tid >> 6;
  const int xoff = wv * 64 + ((lane >> 3) << 3);   // row within 256-row tile
  const int c0 = (lane & 7) << 3;                  // col
  const long gbase = (long)blockIdx.x * 256;
  const int wk = tid >> 4, wc = (tid & 15) << 2;   // W staging slot

  float4 rx[4];
  float4 rw;
  const long gr = gbase + tid;
  const bool rok = gr < (long)N;
  const float* xr = X + gr * K;

  // ---- stage chunk c into registers (global -> reg) ----
  auto loadX = [&](int c) {
    const float* xp = xr + c * 16;
    #pragma unroll
    for (int m = 0; m < 4; ++m) {
      float4 v = make_float4(0.f, 0.f, 0.f, 0.f);
      if (rok) {
        int kk = c * 16 + 4 * m;
        if (kk + 4 <= K) v = *(const float4*)(xp + 4 * m);
        else {
          float t0 = (kk + 0 < K) ? xp[4 * m + 0] : 0.f;
          float t1 = (kk + 1 < K) ? xp[4 * m + 1] : 0.f;
          float t2 = (kk + 2 < K) ? xp[4 * m + 2] : 0.f;
          v = make_float4(t0, t1, t2, 0.f);
        }
      }
      rx[m] = v;
    }
  };
  auto loadW = [&](int c) {
    int gk = c * 16 + wk;
    rw = (gk < K) ? *(const float4*)(W + (size_t)gk * 64 + wc)
                  : make_float4(0.f, 0.f, 0.f, 0.f);
  };
  auto writeLDS = [&](int b) {
    float* xb = sX[b];
    #pragma unroll
    for (int m = 0; m < 4; ++m) {      // transpose to k-major; conflict-free b32
      xb[(4 * m + 0) * 256 + tid] = rx[m].x;
      xb[(4 * m + 1) * 256 + tid] = rx[m].y;
      xb[(4 * m + 2) * 256 + tid] = rx[m].z;
      xb[(4 * m + 3) * 256 + tid] = rx[m].w;
    }
    *(float4*)(sW[b] + wk * 64 + wc) = rw;
  };

  loadX(0); loadW(0); writeLDS(0);

  float acc[64];
  #pragma unroll
  for (int i = 0; i < 64; ++i) acc[i] = 0.f;

  #pragma unroll 1
  for (int c = 0; c < KC; ++c) {
    if (c + 1 < KC) { loadX(c + 1); loadW(c + 1); }   // issue early (T14)
    __syncthreads();
    const float* sXc = sX[c & 1];
    const float* sWc = sW[c & 1];
    #pragma unroll
    for (int k = 0; k < 16; ++k) {
      float4 xa = *(const float4*)(sXc + k * 256 + xoff);
      float4 xb = *(const float4*)(sXc + k * 256 + xoff + 4);
      float4 wa = *(const float4*)(sWc + k * 64 + c0);
      float4 wb = *(const float4*)(sWc + k * 64 + c0 + 4);
      float xr8[8] = {xa.x, xa.y, xa.z, xa.w, xb.x, xb.y, xb.z, xb.w};
      float wc8[8] = {wa.x, wa.y, wa.z, wa.w, wb.x, wb.y, wb.z, wb.w};
      #pragma unroll
      for (int r = 0; r < 8; ++r) {
        #pragma unroll
        for (int q = 0; q < 8; ++q) acc[r * 8 + q] += xr8[r] * wc8[q];
      }
    }
    if (c + 1 < KC) writeLDS((c + 1) & 1);            // write late (other buffer)
  }

  #pragma unroll
  for (int r = 0; r < 8; ++r) {
    long row = gbase + xoff + r;
    if (row < N) {
      float d = disv[row];
      float* yp = Y + row * 64 + c0;
      *(float4*)(yp + 0) = make_float4(acc[r*8+0]*d, acc[r*8+1]*d, acc[r*8+2]*d, acc[r*8+3]*d);
      *(float4*)(yp + 4) = make_float4(acc[r*8+4]*d, acc[r*8+5]*d, acc[r*8+6]*d, acc[r*8+7]*d);
    }
  }
}

// One wave per node: Hout[i] = lrelu( (Hps[i] + sum_{e->i} Hps[src]) * dis[i] + b )
__launch_bounds__(256)
__global__ void k_agg(const float* __restrict__ Hps, const int* __restrict__ offs,
                      const int* __restrict__ csr, const float* __restrict__ dis,
                      const float* __restrict__ bias, float* __restrict__ Hout, int N) {
  int node = blockIdx.x * 4 + (threadIdx.x >> 6);
  if (node >= N) return;
  int lane = threadIdx.x & 63;
  int beg = offs[node], end = offs[node + 1];
  float acc = Hps[(size_t)node * 64 + lane];
  int e = beg;
  for (; e + 4 <= end; e += 4) {
    int s0 = csr[e], s1 = csr[e + 1], s2 = csr[e + 2], s3 = csr[e + 3];
    acc += Hps[(size_t)s0 * 64 + lane];
    acc += Hps[(size_t)s1 * 64 + lane];
    acc += Hps[(size_t)s2 * 64 + lane];
    acc += Hps[(size_t)s3 * 64 + lane];
  }
  for (; e < end; ++e) acc += Hps[(size_t)csr[e] * 64 + lane];
  acc = acc * dis[node] + bias[lane];
  Hout[(size_t)node * 64 + lane] = (acc > 0.f) ? acc : SLOPE * acc;
}

// One wave per graph: mean-pool + fc1 + lrelu + fc2
__launch_bounds__(64)
__global__ void k_pool(const float* __restrict__ H, const int* __restrict__ batch,
                       const float* __restrict__ f1W, const float* __restrict__ f1b,
                       const float* __restrict__ f2W, const float* __restrict__ f2b,
                       float* __restrict__ out, int N) {
  int g = blockIdx.x;
  int lane = threadIdx.x;
  int lo = 0, hi = N;
  while (lo < hi) { int m = (lo + hi) >> 1; if (batch[m] < g) lo = m + 1; else hi = m; }
  int beg = lo;
  hi = N;
  while (lo < hi) { int m = (lo + hi) >> 1; if (batch[m] < g + 1) lo = m + 1; else hi = m; }
  int end = lo;
  float acc = 0.f;
  for (int r = beg; r < end; ++r) acc += H[(size_t)r * 64 + lane];
  float c = (float)(end - beg);
  acc /= (c < 1.f ? 1.f : c);
  __shared__ float p[64];
  p[lane] = acc;
  __syncthreads();
  float q = f1b[lane];
  #pragma unroll
  for (int k = 0; k < 64; ++k) q += p[k] * f1W[k * 64 + lane];
  q = (q > 0.f) ? q : SLOPE * q;
  float v = q * f2W[lane];
  #pragma unroll
  for (int off = 32; off > 0; off >>= 1) v += __shfl_down(v, off, 64);
  if (lane == 0) out[g] = v + f2b[0];
}

extern "C" void kernel_launch(void* const* d_in, const int* in_sizes, int n_in,
                              void* d_out, int out_size, void* d_ws, size_t ws_size,
                              hipStream_t stream) {
  const float* x    = (const float*)d_in[0];
  const int*  eidx  = (const int*)d_in[1];
  const int*  batch = (const int*)d_in[2];
  const float* W0 = (const float*)d_in[3];
  const float* b0 = (const float*)d_in[4];
  const float* W1 = (const float*)d_in[5];
  const float* b1 = (const float*)d_in[6];
  const float* W2 = (const float*)d_in[7];
  const float* b2 = (const float*)d_in[8];
  const float* f1W = (const float*)d_in[9];
  const float* f1b = (const float*)d_in[10];
  const float* f2W = (const float*)d_in[11];
  const float* f2b = (const float*)d_in[12];
  float* out = (float*)d_out;

  const int N = NN, E = NE;
  const int* src  = eidx;
  const int* dstp = eidx + E;

  const size_t NPAD = 100096;
  char* w = (char*)d_ws;
  float* bufA  = (float*)w; w += NPAD * 64 * 4;   // bedge aliases bufA (dead until gemm0)
  float* bufB  = (float*)w; w += NPAD * 64 * 4;
  int*   csr   = (int*)w;   w += (size_t)E * 4;
  int*   offs  = (int*)w;   w += (size_t)(N + 4) * 4;
  float* dis   = (float*)w; w += (size_t)N * 4;
  int*   bh    = (int*)w;   w += (size_t)NBLK * NBUK * 4;
  int*   btot  = (int*)w;   w += (NBUK + 1) * 4;
  int*   boffs = (int*)w;   w += (NBUK + 1) * 4;
  unsigned* bedge = (unsigned*)bufA;

  k_hist<<<NBLK, 256, 0, stream>>>(dstp, bh, E);
  k_bucket_scan<<<NBUK, 256, 0, stream>>>(bh, btot);
  k_btot_scan<<<1, 512, 0, stream>>>(btot, boffs, E);
  k_scatter<<<NBLK, 256, 0, stream>>>(src, dstp, bh, boffs, bedge, E);
  k_b2csr<<<NBUK, 256, 0, stream>>>(bedge, boffs, offs, dis, csr, N);

  const int NTB = (N + 255) / 256;   // 391
  k_gemm<NODE_IN><<<NTB, 256, 0, stream>>>(x, W0, dis, bufA, N);
  k_agg<<<(N + 3) / 4, 256, 0, stream>>>(bufA, offs, csr, dis, b0, bufB, N);
  k_gemm<64><<<NTB, 256, 0, stream>>>(bufB, W1, dis, bufA, N);
  k_agg<<<(N + 3) / 4, 256, 0, stream>>>(bufA, offs, csr, dis, b1, bufB, N);
  k_gemm<64><<<NTB, 256, 0, stream>>>(bufB, W2, dis, bufA, N);
  k_agg<<<(N + 3) / 4, 256, 0, stream>>>(bufA, offs, csr, dis, b2, bufB, N);
  k_pool<<<NG, 64, 0, stream>>>(bufB, batch, f1W, f1b, f2W, f2b, out, N);
}

// Round 9
// 439.414 us; speedup vs baseline: 7.1959x; 1.5149x over previous
//
#include <hip/hip_runtime.h>

#define NN 100000
#define NE 1600000
#define NG 1024
#define NODE_IN 163
#define SLOPE 0.01f
#define NBUK 391      // ceil(100000/256)
#define BUKSH 8       // 256 nodes per bucket
#define EPB 8192      // edges per partition block
#define NBLK ((NE + EPB - 1) / EPB)   // 196

// ---------------- CSR build (privatized counting sort; round-4, verified) -------------
__global__ void k_hist(const int* __restrict__ dst, int* __restrict__ bh, int E) {
  __shared__ int h[NBUK];
  for (int i = threadIdx.x; i < NBUK; i += 256) h[i] = 0;
  __syncthreads();
  int beg = blockIdx.x * EPB, end = min(E, beg + EPB);
  for (int e = beg + threadIdx.x; e < end; e += 256) atomicAdd(&h[dst[e] >> BUKSH], 1);
  __syncthreads();
  for (int i = threadIdx.x; i < NBUK; i += 256) bh[blockIdx.x * NBUK + i] = h[i];
}

__global__ void k_bucket_scan(int* __restrict__ bh, int* __restrict__ btot) {
  __shared__ int s[256];
  int bucket = blockIdx.x, tid = threadIdx.x;
  int v = (tid < NBLK) ? bh[tid * NBUK + bucket] : 0;
  s[tid] = v;
  __syncthreads();
  for (int off = 1; off < 256; off <<= 1) {
    int t = (tid >= off) ? s[tid - off] : 0;
    __syncthreads();
    s[tid] += t;
    __syncthreads();
  }
  if (tid < NBLK) bh[tid * NBUK + bucket] = s[tid] - v;
  if (tid == 255) btot[bucket] = s[255];
}

__global__ void k_btot_scan(const int* __restrict__ btot, int* __restrict__ boffs, int E) {
  __shared__ int s[512];
  int tid = threadIdx.x;
  int v = (tid < NBUK) ? btot[tid] : 0;
  s[tid] = v;
  __syncthreads();
  for (int off = 1; off < 512; off <<= 1) {
    int t = (tid >= off) ? s[tid - off] : 0;
    __syncthreads();
    s[tid] += t;
    __syncthreads();
  }
  if (tid < NBUK) boffs[tid] = s[tid] - v;
  if (tid == 0) boffs[NBUK] = E;
}

__global__ void k_scatter(const int* __restrict__ src, const int* __restrict__ dst,
                          const int* __restrict__ bh, const int* __restrict__ boffs,
                          unsigned* __restrict__ bedge, int E) {
  __shared__ int cur[NBUK];
  for (int i = threadIdx.x; i < NBUK; i += 256)
    cur[i] = boffs[i] + bh[blockIdx.x * NBUK + i];
  __syncthreads();
  int beg = blockIdx.x * EPB, end = min(E, beg + EPB);
  for (int e = beg + threadIdx.x; e < end; e += 256) {
    int d = dst[e];
    int pos = atomicAdd(&cur[d >> BUKSH], 1);
    bedge[pos] = (unsigned)src[e] | ((unsigned)(d & 255) << 17);
  }
}

__global__ void k_b2csr(const unsigned* __restrict__ bedge, const int* __restrict__ boffs,
                        int* __restrict__ offs, float* __restrict__ dis,
                        int* __restrict__ csr, int N) {
  __shared__ int lcnt[256];
  __shared__ int s[256];
  __shared__ int lcur[256];
  int b = blockIdx.x, tid = threadIdx.x;
  int beg = boffs[b], end = boffs[b + 1];
  lcnt[tid] = 0;
  __syncthreads();
  for (int e = beg + tid; e < end; e += 256) atomicAdd(&lcnt[bedge[e] >> 17], 1);
  __syncthreads();
  int v = lcnt[tid];
  s[tid] = v;
  __syncthreads();
  for (int off = 1; off < 256; off <<= 1) {
    int t = (tid >= off) ? s[tid - off] : 0;
    __syncthreads();
    s[tid] += t;
    __syncthreads();
  }
  int o = s[tid] - v;
  int node = (b << BUKSH) + tid;
  if (node <= N) offs[node] = beg + o;
  if (node < N) dis[node] = rsqrtf((float)(v + 1));
  lcur[tid] = o;
  __syncthreads();
  for (int e = beg + tid; e < end; e += 256) {
    unsigned w = bedge[e];
    int p = atomicAdd(&lcur[w >> 17], 1);
    csr[beg + p] = (int)(w & 0x1FFFFu);
  }
}

// ---------------- GEMM: 128-row tile, 8x4 microtile, k-major X in LDS -----------------
// Wave = 32 rows x 64 cols; lane: rows xoff..xoff+7 (contig), cols c0..c0+3.
// acc = 32 regs; total demand ~80 VGPR -> fits the 128-VGPR tier (LDS 24KB -> 4+ blk/CU)
// with margin, so the allocator cannot spill (rounds 6-8 post-mortem: 64-acc microtile
// spilled at every occupancy tier the compiler picked).
template<int K>
__launch_bounds__(256)
__global__ void k_gemm(const float* __restrict__ X, const float* __restrict__ W,
                       const float* __restrict__ disv, float* __restrict__ Y, int N) {
  constexpr int KC = (K + 15) >> 4;
  __shared__ float sX[2][16 * 128];
  __shared__ float sW[2][16 * 64];
  const int tid = threadIdx.x;
  const int lane = tid & 63, wv = tid >> 6;
  const int xoff = wv * 32 + ((lane >> 4) << 3);   // row within 128-row tile
  const int c0 = (lane & 15) << 2;                 // col
  const long gbase = (long)blockIdx.x * 128;
  const int srow = tid >> 1, koff = (tid & 1) << 3; // X staging: row, k-offset
  const int wk = tid >> 4, wc = (tid & 15) << 2;    // W staging slot

  float4 rx[2];
  float4 rw;
  const long gr = gbase + srow;
  const bool rok = gr < (long)N;
  const float* xr = X + gr * K + koff;

  auto loadX = [&](int c) {
    #pragma unroll
    for (int m = 0; m < 2; ++m) {
      float4 v = make_float4(0.f, 0.f, 0.f, 0.f);
      if (rok) {
        int kk = c * 16 + koff + 4 * m;
        if (kk + 4 <= K) v = *(const float4*)(xr + c * 16 + 4 * m);
        else {
          const float* p = xr + c * 16 + 4 * m;
          float t0 = (kk + 0 < K) ? p[0] : 0.f;
          float t1 = (kk + 1 < K) ? p[1] : 0.f;
          float t2 = (kk + 2 < K) ? p[2] : 0.f;
          v = make_float4(t0, t1, t2, 0.f);
        }
      }
      rx[m] = v;
    }
  };
  auto loadW = [&](int c) {
    int gk = c * 16 + wk;
    rw = (gk < K) ? *(const float4*)(W + (size_t)gk * 64 + wc)
                  : make_float4(0.f, 0.f, 0.f, 0.f);
  };
  auto writeLDS = [&](int b) {
    float* xb = sX[b];
    #pragma unroll
    for (int m = 0; m < 2; ++m) {      // k-major transpose; 2-way bank alias (free)
      xb[(koff + 4 * m + 0) * 128 + srow] = rx[m].x;
      xb[(koff + 4 * m + 1) * 128 + srow] = rx[m].y;
      xb[(koff + 4 * m + 2) * 128 + srow] = rx[m].z;
      xb[(koff + 4 * m + 3) * 128 + srow] = rx[m].w;
    }
    *(float4*)(sW[b] + wk * 64 + wc) = rw;
  };

  loadX(0); loadW(0); writeLDS(0);

  float acc[32];
  #pragma unroll
  for (int i = 0; i < 32; ++i) acc[i] = 0.f;

  #pragma unroll 1
  for (int c = 0; c < KC; ++c) {
    if (c + 1 < KC) { loadX(c + 1); loadW(c + 1); }   // issue early (T14)
    __syncthreads();
    const float* sXc = sX[c & 1];
    const float* sWc = sW[c & 1];
    #pragma unroll
    for (int k = 0; k < 16; ++k) {
      float4 xa = *(const float4*)(sXc + k * 128 + xoff);      // 16-lane broadcast
      float4 xb = *(const float4*)(sXc + k * 128 + xoff + 4);
      float4 wr = *(const float4*)(sWc + k * 64 + c0);         // 2-way alias (free)
      float xr8[8] = {xa.x, xa.y, xa.z, xa.w, xb.x, xb.y, xb.z, xb.w};
      #pragma unroll
      for (int r = 0; r < 8; ++r) {
        acc[r * 4 + 0] += xr8[r] * wr.x;
        acc[r * 4 + 1] += xr8[r] * wr.y;
        acc[r * 4 + 2] += xr8[r] * wr.z;
        acc[r * 4 + 3] += xr8[r] * wr.w;
      }
    }
    if (c + 1 < KC) writeLDS((c + 1) & 1);            // write late (other buffer)
  }

  #pragma unroll
  for (int r = 0; r < 8; ++r) {
    long row = gbase + xoff + r;
    if (row < N) {
      float d = disv[row];
      *(float4*)(Y + row * 64 + c0) =
          make_float4(acc[r*4+0]*d, acc[r*4+1]*d, acc[r*4+2]*d, acc[r*4+3]*d);
    }
  }
}

// One wave per node: Hout[i] = lrelu( (Hps[i] + sum_{e->i} Hps[src]) * dis[i] + b )
__launch_bounds__(256)
__global__ void k_agg(const float* __restrict__ Hps, const int* __restrict__ offs,
                      const int* __restrict__ csr, const float* __restrict__ dis,
                      const float* __restrict__ bias, float* __restrict__ Hout, int N) {
  int node = blockIdx.x * 4 + (threadIdx.x >> 6);
  if (node >= N) return;
  int lane = threadIdx.x & 63;
  int beg = offs[node], end = offs[node + 1];
  float acc = Hps[(size_t)node * 64 + lane];
  int e = beg;
  for (; e + 4 <= end; e += 4) {
    int s0 = csr[e], s1 = csr[e + 1], s2 = csr[e + 2], s3 = csr[e + 3];
    acc += Hps[(size_t)s0 * 64 + lane];
    acc += Hps[(size_t)s1 * 64 + lane];
    acc += Hps[(size_t)s2 * 64 + lane];
    acc += Hps[(size_t)s3 * 64 + lane];
  }
  for (; e < end; ++e) acc += Hps[(size_t)csr[e] * 64 + lane];
  acc = acc * dis[node] + bias[lane];
  Hout[(size_t)node * 64 + lane] = (acc > 0.f) ? acc : SLOPE * acc;
}

// One wave per graph: mean-pool + fc1 + lrelu + fc2
__launch_bounds__(64)
__global__ void k_pool(const float* __restrict__ H, const int* __restrict__ batch,
                       const float* __restrict__ f1W, const float* __restrict__ f1b,
                       const float* __restrict__ f2W, const float* __restrict__ f2b,
                       float* __restrict__ out, int N) {
  int g = blockIdx.x;
  int lane = threadIdx.x;
  int lo = 0, hi = N;
  while (lo < hi) { int m = (lo + hi) >> 1; if (batch[m] < g) lo = m + 1; else hi = m; }
  int beg = lo;
  hi = N;
  while (lo < hi) { int m = (lo + hi) >> 1; if (batch[m] < g + 1) lo = m + 1; else hi = m; }
  int end = lo;
  float acc = 0.f;
  for (int r = beg; r < end; ++r) acc += H[(size_t)r * 64 + lane];
  float c = (float)(end - beg);
  acc /= (c < 1.f ? 1.f : c);
  __shared__ float p[64];
  p[lane] = acc;
  __syncthreads();
  float q = f1b[lane];
  #pragma unroll
  for (int k = 0; k < 64; ++k) q += p[k] * f1W[k * 64 + lane];
  q = (q > 0.f) ? q : SLOPE * q;
  float v = q * f2W[lane];
  #pragma unroll
  for (int off = 32; off > 0; off >>= 1) v += __shfl_down(v, off, 64);
  if (lane == 0) out[g] = v + f2b[0];
}

extern "C" void kernel_launch(void* const* d_in, const int* in_sizes, int n_in,
                              void* d_out, int out_size, void* d_ws, size_t ws_size,
                              hipStream_t stream) {
  const float* x    = (const float*)d_in[0];
  const int*  eidx  = (const int*)d_in[1];
  const int*  batch = (const int*)d_in[2];
  const float* W0 = (const float*)d_in[3];
  const float* b0 = (const float*)d_in[4];
  const float* W1 = (const float*)d_in[5];
  const float* b1 = (const float*)d_in[6];
  const float* W2 = (const float*)d_in[7];
  const float* b2 = (const float*)d_in[8];
  const float* f1W = (const float*)d_in[9];
  const float* f1b = (const float*)d_in[10];
  const float* f2W = (const float*)d_in[11];
  const float* f2b = (const float*)d_in[12];
  float* out = (float*)d_out;

  const int N = NN, E = NE;
  const int* src  = eidx;
  const int* dstp = eidx + E;

  const size_t NPAD = 100096;
  char* w = (char*)d_ws;
  float* bufA  = (float*)w; w += NPAD * 64 * 4;   // bedge aliases bufA (dead until gemm0)
  float* bufB  = (float*)w; w += NPAD * 64 * 4;
  int*   csr   = (int*)w;   w += (size_t)E * 4;
  int*   offs  = (int*)w;   w += (size_t)(N + 4) * 4;
  float* dis   = (float*)w; w += (size_t)N * 4;
  int*   bh    = (int*)w;   w += (size_t)NBLK * NBUK * 4;
  int*   btot  = (int*)w;   w += (NBUK + 1) * 4;
  int*   boffs = (int*)w;   w += (NBUK + 1) * 4;
  unsigned* bedge = (unsigned*)bufA;

  k_hist<<<NBLK, 256, 0, stream>>>(dstp, bh, E);
  k_bucket_scan<<<NBUK, 256, 0, stream>>>(bh, btot);
  k_btot_scan<<<1, 512, 0, stream>>>(btot, boffs, E);
  k_scatter<<<NBLK, 256, 0, stream>>>(src, dstp, bh, boffs, bedge, E);
  k_b2csr<<<NBUK, 256, 0, stream>>>(bedge, boffs, offs, dis, csr, N);

  const int NTB = (N + 127) / 128;   // 782
  k_gemm<NODE_IN><<<NTB, 256, 0, stream>>>(x, W0, dis, bufA, N);
  k_agg<<<(N + 3) / 4, 256, 0, stream>>>(bufA, offs, csr, dis, b0, bufB, N);
  k_gemm<64><<<NTB, 256, 0, stream>>>(bufB, W1, dis, bufA, N);
  k_agg<<<(N + 3) / 4, 256, 0, stream>>>(bufA, offs, csr, dis, b1, bufB, N);
  k_gemm<64><<<NTB, 256, 0, stream>>>(bufB, W2, dis, bufA, N);
  k_agg<<<(N + 3) / 4, 256, 0, stream>>>(bufA, offs, csr, dis, b2, bufB, N);
  k_pool<<<NG, 64, 0, stream>>>(bufB, batch, f1W, f1b, f2W, f2b, out, N);
}